// Round 1
// baseline (14204.808 us; speedup 1.0000x reference)
//
#include <hip/hip_runtime.h>
#include <math.h>

// ---- problem constants (match reference) ----
#define D     1024
#define NH    8
#define DHD   128
#define NL    12
#define NE    4
#define FF    2048
#define NCLS  10
#define BB    4
#define SS    512
#define TT    (BB*SS)          // 2048 tokens
#define EPSV  1e-5f
#define SPARS 0.5f

// =====================================================================
// GEMM: C[M,N] = act(A[M,K] @ Bw[N,K]^T + bias[N])
// requires M%64==0, N%64==0, K%16==0
// ACT: 0 = identity, 1 = exact GELU
// =====================================================================
template<int ACT>
__global__ __launch_bounds__(256)
void gemm_bias(const float* __restrict__ A, const float* __restrict__ Bw,
               const float* __restrict__ bias, float* __restrict__ C,
               int M, int N, int K)
{
    __shared__ float As[16][68];   // k-major, pad 4 -> 16B-aligned rows, 2-way max bank alias
    __shared__ float Bs[16][68];
    const int tid = threadIdx.x;
    const int m0 = blockIdx.y * 64;
    const int n0 = blockIdx.x * 64;
    const int tm = (tid >> 4) << 2;      // 0..60
    const int tn = (tid & 15) << 2;      // 0..60
    const int lr = tid >> 2;             // 0..63 tile row
    const int lk = (tid & 3) << 2;       // 0,4,8,12
    const float* Arow = A + (size_t)(m0 + lr) * K + lk;
    const float* Brow = Bw + (size_t)(n0 + lr) * K + lk;
    float acc[4][4] = {};
    for (int k0 = 0; k0 < K; k0 += 16) {
        float4 av = *reinterpret_cast<const float4*>(Arow + k0);
        float4 bv = *reinterpret_cast<const float4*>(Brow + k0);
        __syncthreads();
        As[lk+0][lr]=av.x; As[lk+1][lr]=av.y; As[lk+2][lr]=av.z; As[lk+3][lr]=av.w;
        Bs[lk+0][lr]=bv.x; Bs[lk+1][lr]=bv.y; Bs[lk+2][lr]=bv.z; Bs[lk+3][lr]=bv.w;
        __syncthreads();
        #pragma unroll
        for (int k = 0; k < 16; ++k) {
            float aa[4], bb[4];
            *reinterpret_cast<float4*>(aa) = *reinterpret_cast<const float4*>(&As[k][tm]);
            *reinterpret_cast<float4*>(bb) = *reinterpret_cast<const float4*>(&Bs[k][tn]);
            #pragma unroll
            for (int i = 0; i < 4; ++i)
                #pragma unroll
                for (int j = 0; j < 4; ++j)
                    acc[i][j] += aa[i]*bb[j];
        }
    }
    const float* bptr = bias + n0 + tn;
    float bb4[4] = {bptr[0], bptr[1], bptr[2], bptr[3]};
    #pragma unroll
    for (int i = 0; i < 4; ++i) {
        float4 ov;
        float* crow = C + (size_t)(m0+tm+i)*N + n0 + tn;
        float v[4];
        #pragma unroll
        for (int j = 0; j < 4; ++j) {
            float u = acc[i][j] + bb4[j];
            if (ACT == 1) u = 0.5f*u*(1.0f + erff(u*0.70710678118654752f));
            v[j] = u;
        }
        ov.x=v[0]; ov.y=v[1]; ov.z=v[2]; ov.w=v[3];
        *reinterpret_cast<float4*>(crow) = ov;
    }
}

// =====================================================================
// Attention: per block = one (b,h) and 16 queries; full softmax over S=512
// qkv layout: [token][3*D], q at col h*DHD, k at D + h*DHD, v at 2D + h*DHD
// =====================================================================
#define QT 16
#define KT 32
__global__ __launch_bounds__(256)
void attn_kernel(const float* __restrict__ qkv, float* __restrict__ o)
{
    __shared__ float Qs[QT][DHD+1];
    __shared__ float Ks[KT][DHD+1];
    __shared__ float Sc[QT][SS+16];
    const int tid = threadIdx.x;
    const int bh = blockIdx.y;
    const int b = bh >> 3, h = bh & 7;
    const int q0 = blockIdx.x * QT;
    const size_t rs = 3*D;
    const float* qb = qkv + (size_t)b*SS*rs;
    // load Q tile
    for (int i = tid; i < QT*(DHD/4); i += 256) {
        int q = i >> 5, dc = (i & 31) << 2;
        float4 v = *reinterpret_cast<const float4*>(qb + (size_t)(q0+q)*rs + h*DHD + dc);
        Qs[q][dc]=v.x; Qs[q][dc+1]=v.y; Qs[q][dc+2]=v.z; Qs[q][dc+3]=v.w;
    }
    const float scale = 0.08838834764831845f;  // 1/sqrt(128)
    for (int kt = 0; kt < SS; kt += KT) {
        __syncthreads();
        for (int i = tid; i < KT*(DHD/4); i += 256) {
            int kk = i >> 5, dc = (i & 31) << 2;
            float4 v = *reinterpret_cast<const float4*>(qb + (size_t)(kt+kk)*rs + D + h*DHD + dc);
            Ks[kk][dc]=v.x; Ks[kk][dc+1]=v.y; Ks[kk][dc+2]=v.z; Ks[kk][dc+3]=v.w;
        }
        __syncthreads();
        for (int t = tid; t < QT*KT; t += 256) {
            int q = t >> 5, kk = t & 31;
            float s = 0.f;
            #pragma unroll 8
            for (int d = 0; d < DHD; ++d) s += Qs[q][d]*Ks[kk][d];
            Sc[q][kt+kk] = s*scale;
        }
    }
    __syncthreads();
    // softmax: 16 consecutive lanes per query
    {
        const int q = tid >> 4, lane = tid & 15;
        float mx = -1e30f;
        for (int j = lane; j < SS; j += 16) mx = fmaxf(mx, Sc[q][j]);
        #pragma unroll
        for (int off = 8; off; off >>= 1) mx = fmaxf(mx, __shfl_xor(mx, off, 16));
        float sum = 0.f;
        for (int j = lane; j < SS; j += 16) { float e = __expf(Sc[q][j]-mx); Sc[q][j]=e; sum += e; }
        #pragma unroll
        for (int off = 8; off; off >>= 1) sum += __shfl_xor(sum, off, 16);
        const float inv = 1.0f/sum;
        for (int j = lane; j < SS; j += 16) Sc[q][j] *= inv;
    }
    // P @ V
    const int q = tid >> 4;
    const int dbase = (tid & 15) << 3;
    float acc[8] = {};
    for (int kt = 0; kt < SS; kt += KT) {
        __syncthreads();
        for (int i = tid; i < KT*(DHD/4); i += 256) {
            int kk = i >> 5, dc = (i & 31) << 2;
            float4 v = *reinterpret_cast<const float4*>(qb + (size_t)(kt+kk)*rs + 2*D + h*DHD + dc);
            Ks[kk][dc]=v.x; Ks[kk][dc+1]=v.y; Ks[kk][dc+2]=v.z; Ks[kk][dc+3]=v.w;
        }
        __syncthreads();
        #pragma unroll 4
        for (int kk = 0; kk < KT; ++kk) {
            float p = Sc[q][kt+kk];
            #pragma unroll
            for (int j = 0; j < 8; ++j) acc[j] += p*Ks[kk][dbase+j];
        }
    }
    float* orow = o + (size_t)(b*SS + q0 + q)*D + h*DHD + dbase;
    #pragma unroll
    for (int j = 0; j < 8; ++j) orow[j] = acc[j];
}

// =====================================================================
// fused residual + LayerNorm: xout = LN(xin + delta) * s + b  (row = block)
// =====================================================================
__global__ __launch_bounds__(256)
void add_ln(const float* __restrict__ xin, const float* __restrict__ delta,
            const float* __restrict__ gs, const float* __restrict__ gb,
            float* __restrict__ xout)
{
    const int row = blockIdx.x, tid = threadIdx.x;
    const size_t off = (size_t)row*D + tid*4;
    float4 a  = *reinterpret_cast<const float4*>(xin + off);
    float4 dd = *reinterpret_cast<const float4*>(delta + off);
    float v0=a.x+dd.x, v1=a.y+dd.y, v2=a.z+dd.z, v3=a.w+dd.w;
    __shared__ float red[2][4];
    float s = v0+v1+v2+v3;
    #pragma unroll
    for (int o = 32; o; o >>= 1) s += __shfl_xor(s, o, 64);
    if ((tid & 63) == 0) red[0][tid>>6] = s;
    __syncthreads();
    const float mean = (red[0][0]+red[0][1]+red[0][2]+red[0][3]) * (1.0f/D);
    v0-=mean; v1-=mean; v2-=mean; v3-=mean;
    float qv = v0*v0+v1*v1+v2*v2+v3*v3;
    #pragma unroll
    for (int o = 32; o; o >>= 1) qv += __shfl_xor(qv, o, 64);
    if ((tid & 63) == 0) red[1][tid>>6] = qv;
    __syncthreads();
    const float var = (red[1][0]+red[1][1]+red[1][2]+red[1][3]) * (1.0f/D);
    const float rstd = rsqrtf(var + EPSV);
    float4 sv = *reinterpret_cast<const float4*>(gs + tid*4);
    float4 bv = *reinterpret_cast<const float4*>(gb + tid*4);
    float4 ov;
    ov.x = v0*rstd*sv.x + bv.x;
    ov.y = v1*rstd*sv.y + bv.y;
    ov.z = v2*rstd*sv.z + bv.z;
    ov.w = v3*rstd*sv.w + bv.w;
    *reinterpret_cast<float4*>(xout + off) = ov;
}

// =====================================================================
// gate: logits = x@Wg^T + bg -> softmax -> top2 (first-occurrence ties)
// =====================================================================
__global__ __launch_bounds__(256)
void gate_kernel(const float* __restrict__ x, const float* __restrict__ Wg,
                 const float* __restrict__ bg, float* __restrict__ gv, int* __restrict__ gi)
{
    const int t = blockIdx.x, tid = threadIdx.x;
    const float* xr = x + (size_t)t*D;
    float p0=0,p1=0,p2=0,p3=0;
    for (int d = tid; d < D; d += 256) {
        const float xv = xr[d];
        p0 += xv*Wg[d]; p1 += xv*Wg[D+d]; p2 += xv*Wg[2*D+d]; p3 += xv*Wg[3*D+d];
    }
    #pragma unroll
    for (int o = 32; o; o >>= 1) {
        p0 += __shfl_xor(p0, o, 64); p1 += __shfl_xor(p1, o, 64);
        p2 += __shfl_xor(p2, o, 64); p3 += __shfl_xor(p3, o, 64);
    }
    __shared__ float red[4][4];
    if ((tid & 63) == 0) { const int w = tid>>6; red[w][0]=p0; red[w][1]=p1; red[w][2]=p2; red[w][3]=p3; }
    __syncthreads();
    if (tid == 0) {
        float g[4];
        #pragma unroll
        for (int e = 0; e < 4; ++e) g[e] = red[0][e]+red[1][e]+red[2][e]+red[3][e] + bg[e];
        const float mx = fmaxf(fmaxf(g[0],g[1]), fmaxf(g[2],g[3]));
        float ssum = 0.f;
        #pragma unroll
        for (int e = 0; e < 4; ++e) { g[e] = __expf(g[e]-mx); ssum += g[e]; }
        const float inv = 1.0f/ssum;
        #pragma unroll
        for (int e = 0; e < 4; ++e) g[e] *= inv;
        int i0 = 0;
        for (int e = 1; e < 4; ++e) if (g[e] > g[i0]) i0 = e;
        int i1 = (i0 == 0) ? 1 : 0;
        for (int e = 0; e < 4; ++e) if (e != i0 && g[e] > g[i1]) i1 = e;
        gv[t*2]   = g[i0]; gv[t*2+1] = g[i1];
        gi[t*2]   = i0;    gi[t*2+1] = i1;
    }
}

// =====================================================================
// MoE combine: x = x*(1-s) + s*(v0*E[i0] + v1*E[i1])   (eo includes be)
// =====================================================================
__global__ __launch_bounds__(256)
void moe_combine(float* __restrict__ x, const float* __restrict__ eo,
                 const float* __restrict__ gv, const int* __restrict__ gi)
{
    const size_t i = (size_t)blockIdx.x*256 + threadIdx.x;   // < TT*D
    const int t = (int)(i >> 10);                            // /D (D=1024)
    const float w0 = gv[t*2]*SPARS, w1 = gv[t*2+1]*SPARS;
    const size_t TD = (size_t)TT*D;
    const float e0 = eo[(size_t)gi[t*2]*TD + i];
    const float e1 = eo[(size_t)gi[t*2+1]*TD + i];
    x[i] = x[i]*(1.0f-SPARS) + w0*e0 + w1*e1;
}

__global__ __launch_bounds__(256)
void addpos(const float* __restrict__ xin, const float* __restrict__ pos, float* __restrict__ xo)
{
    const size_t i = (size_t)blockIdx.x*256 + threadIdx.x;   // < BB*SS*D
    xo[i] = xin[i] + pos[i & ((size_t)SS*D - 1)];            // SS*D = 2^19
}

__global__ __launch_bounds__(64)
void final_kernel(const float* __restrict__ x, const float* __restrict__ Wf,
                  const float* __restrict__ bf, float* __restrict__ out)
{
    const int b = blockIdx.x / NCLS, n = blockIdx.x % NCLS;
    const float* xr = x + ((size_t)b*SS + SS-1)*D;
    const int tid = threadIdx.x;
    float s = 0.f;
    for (int d = tid; d < D; d += 64) s += xr[d]*Wf[(size_t)n*D + d];
    #pragma unroll
    for (int o = 32; o; o >>= 1) s += __shfl_xor(s, o, 64);
    if (tid == 0) out[b*NCLS + n] = s + bf[n];
}

// =====================================================================
extern "C" void kernel_launch(void* const* d_in, const int* in_sizes, int n_in,
                              void* d_out, int out_size, void* d_ws, size_t ws_size,
                              hipStream_t stream)
{
    const float* x_in = (const float*)d_in[0];
    const float* pos  = (const float*)d_in[1];
    const float* Wqkv = (const float*)d_in[2];
    const float* bqkv = (const float*)d_in[3];
    const float* Wo   = (const float*)d_in[4];
    const float* bo   = (const float*)d_in[5];
    const float* ln1s = (const float*)d_in[6];
    const float* ln1b = (const float*)d_in[7];
    const float* W1   = (const float*)d_in[8];
    const float* b1   = (const float*)d_in[9];
    const float* W2   = (const float*)d_in[10];
    const float* b2   = (const float*)d_in[11];
    const float* ln2s = (const float*)d_in[12];
    const float* ln2b = (const float*)d_in[13];
    const float* Wg   = (const float*)d_in[14];
    const float* bg   = (const float*)d_in[15];
    const float* We   = (const float*)d_in[16];
    const float* be   = (const float*)d_in[17];
    const float* Wf   = (const float*)d_in[18];
    const float* bf   = (const float*)d_in[19];
    float* out = (float*)d_out;

    // workspace layout (floats): total ~14.7M floats ~= 59 MB
    float* ws     = (float*)d_ws;
    float* xbuf   = ws;                          // TT*D      (8 MB)
    float* qkvbuf = xbuf   + (size_t)TT*D;       // TT*3D     (24 MB)
    float* hbuf   = qkvbuf + (size_t)TT*3*D;     // TT*FF     (16 MB)
    float* obuf   = hbuf   + (size_t)TT*FF;      // TT*D      (8 MB)
    float* gv     = obuf   + (size_t)TT*D;       // TT*2
    int*   gi     = (int*)(gv + (size_t)TT*2);   // TT*2
    // expert outputs alias the (dead at that point) qkv+h region: NE*TT*D = 8.39M floats <= 10.5M
    float* ebuf   = qkvbuf;

    const dim3 blk(256);
    addpos<<<dim3(TT*D/256), blk, 0, stream>>>(x_in, pos, xbuf);

    for (int l = 0; l < NL; ++l) {
        // qkv = x @ Wqkv^T + b
        gemm_bias<0><<<dim3(3*D/64, TT/64), blk, 0, stream>>>(
            xbuf, Wqkv + (size_t)l*3*D*D, bqkv + (size_t)l*3*D, qkvbuf, TT, 3*D, D);
        // attention -> obuf
        attn_kernel<<<dim3(SS/QT, BB*NH), blk, 0, stream>>>(qkvbuf, obuf);
        // o-proj -> hbuf (temp)
        gemm_bias<0><<<dim3(D/64, TT/64), blk, 0, stream>>>(
            obuf, Wo + (size_t)l*D*D, bo + (size_t)l*D, hbuf, TT, D, D);
        // x = LN(x + oproj)
        add_ln<<<dim3(TT), blk, 0, stream>>>(xbuf, hbuf, ln1s + (size_t)l*D, ln1b + (size_t)l*D, xbuf);
        // h = gelu(x @ W1^T + b1)
        gemm_bias<1><<<dim3(FF/64, TT/64), blk, 0, stream>>>(
            xbuf, W1 + (size_t)l*FF*D, b1 + (size_t)l*FF, hbuf, TT, FF, D);
        // f2 = h @ W2^T + b2 -> obuf
        gemm_bias<0><<<dim3(D/64, TT/64), blk, 0, stream>>>(
            hbuf, W2 + (size_t)l*D*FF, b2 + (size_t)l*D, obuf, TT, D, FF);
        // x = LN(x + f2)
        add_ln<<<dim3(TT), blk, 0, stream>>>(xbuf, obuf, ln2s + (size_t)l*D, ln2b + (size_t)l*D, xbuf);
        // gate + top2
        gate_kernel<<<dim3(TT), blk, 0, stream>>>(xbuf, Wg, bg, gv, gi);
        // all 4 expert outputs (incl. be)
        for (int e = 0; e < NE; ++e)
            gemm_bias<0><<<dim3(D/64, TT/64), blk, 0, stream>>>(
                xbuf, We + (size_t)e*D*D, be + (size_t)e*D, ebuf + (size_t)e*TT*D, TT, D, D);
        // x = x*0.5 + 0.5*(v0*E0 + v1*E1)
        moe_combine<<<dim3(TT*D/256), blk, 0, stream>>>(xbuf, ebuf, gv, gi);
    }
    final_kernel<<<dim3(BB*NCLS), dim3(64), 0, stream>>>(xbuf, Wf, bf, out);
}

// Round 2
// 6161.106 us; speedup vs baseline: 2.3056x; 2.3056x over previous
//
#include <hip/hip_runtime.h>
#include <math.h>

// ---- problem constants (match reference) ----
#define D     1024
#define NH    8
#define DHD   128
#define NL    12
#define NE    4
#define FF    2048
#define NCLS  10
#define BB    4
#define SS    512
#define TT    (BB*SS)          // 2048 tokens
#define EPSV  1e-5f
#define SPARS 0.5f

typedef __attribute__((ext_vector_type(8))) short bf16x8;
typedef __attribute__((ext_vector_type(4))) float f32x4;

__device__ __forceinline__ unsigned short f2bf(float f) {
    unsigned u = __float_as_uint(f);
    u += 0x7FFF + ((u >> 16) & 1);      // RNE
    return (unsigned short)(u >> 16);
}

// =====================================================================
// MFMA GEMM: C[M,N] = act(A[M,K] @ Bw[N,K]^T + bias[N])
// fp32 in global, bf16 conversion at LDS staging, fp32 accum/out.
// 128x128 tile, BK=32, 4 waves each owning a 64x64 quadrant (4x4 frags).
// blockIdx.z batches experts: Bw += z*eBw, bias += z*eBias, C += z*eC.
// requires M%128==0, N%128==0, K%32==0
// =====================================================================
#define LDP 40   // LDS row pitch in bf16 elems (32 data + 8 pad)

template<int ACT>
__global__ __launch_bounds__(256)
void gemm_mfma(const float* __restrict__ A, const float* __restrict__ Bw,
               const float* __restrict__ bias, float* __restrict__ C,
               int M, int N, int K, long eBw, long eBias, long eC)
{
    const int z = blockIdx.z;
    Bw   += (size_t)z * eBw;
    bias += (size_t)z * eBias;
    C    += (size_t)z * eC;

    __shared__ unsigned short Asl[128 * LDP];
    __shared__ unsigned short Bsl[128 * LDP];

    const int tid  = threadIdx.x;
    const int wave = tid >> 6, lane = tid & 63;
    const int wm = (wave >> 1) * 64;     // wave row quadrant
    const int wn = (wave & 1) * 64;      // wave col quadrant
    const int fr = lane & 15;            // fragment row/col select
    const int fq = lane >> 4;            // k-group (0..3)

    const int m0 = blockIdx.y * 128;
    const int n0 = blockIdx.x * 128;

    const int srow = tid >> 3;           // staging row 0..31
    const int scb  = tid & 7;            // staging col-block (4 floats)
    const float* Ag = A  + (size_t)(m0 + srow) * K + scb * 4;
    const float* Bg = Bw + (size_t)(n0 + srow) * K + scb * 4;

    f32x4 acc[4][4] = {};

    for (int k0 = 0; k0 < K; k0 += 32) {
        float4 av[4], bv[4];
        #pragma unroll
        for (int p = 0; p < 4; ++p) {
            av[p] = *reinterpret_cast<const float4*>(Ag + (size_t)(32*p) * K + k0);
            bv[p] = *reinterpret_cast<const float4*>(Bg + (size_t)(32*p) * K + k0);
        }
        __syncthreads();   // previous iteration's frag reads complete
        #pragma unroll
        for (int p = 0; p < 4; ++p) {
            const int r = srow + 32*p;
            ushort4 a4; a4.x=f2bf(av[p].x); a4.y=f2bf(av[p].y); a4.z=f2bf(av[p].z); a4.w=f2bf(av[p].w);
            ushort4 b4; b4.x=f2bf(bv[p].x); b4.y=f2bf(bv[p].y); b4.z=f2bf(bv[p].z); b4.w=f2bf(bv[p].w);
            *reinterpret_cast<ushort4*>(&Asl[r*LDP + scb*4]) = a4;
            *reinterpret_cast<ushort4*>(&Bsl[r*LDP + scb*4]) = b4;
        }
        __syncthreads();

        bf16x8 af[4], bf_[4];
        #pragma unroll
        for (int i = 0; i < 4; ++i) {
            af[i]  = *reinterpret_cast<const bf16x8*>(&Asl[(wm + i*16 + fr)*LDP + fq*8]);
            bf_[i] = *reinterpret_cast<const bf16x8*>(&Bsl[(wn + i*16 + fr)*LDP + fq*8]);
        }
        #pragma unroll
        for (int i = 0; i < 4; ++i)
            #pragma unroll
            for (int j = 0; j < 4; ++j)
                acc[i][j] = __builtin_amdgcn_mfma_f32_16x16x32_bf16(af[i], bf_[j], acc[i][j], 0, 0, 0);
    }

    // epilogue: C[m0+wm+i*16+fq*4+r][n0+wn+j*16+fr]
    #pragma unroll
    for (int j = 0; j < 4; ++j) {
        const int n = n0 + wn + j*16 + fr;
        const float bb = bias[n];
        #pragma unroll
        for (int i = 0; i < 4; ++i) {
            const int mbase = m0 + wm + i*16 + fq*4;
            #pragma unroll
            for (int r = 0; r < 4; ++r) {
                float u = acc[i][j][r] + bb;
                if (ACT == 1) u = 0.5f*u*(1.0f + erff(u*0.70710678118654752f));
                C[(size_t)(mbase + r) * N + n] = u;
            }
        }
    }
}

// =====================================================================
// Attention: per block = one (b,h) and 16 queries; full softmax over S=512
// qkv layout: [token][3*D], q at col h*DHD, k at D + h*DHD, v at 2D + h*DHD
// float4-vectorized LDS reads; rows padded +4 for 16B alignment.
// =====================================================================
#define QT 16
#define KT 32
__global__ __launch_bounds__(256)
void attn_kernel(const float* __restrict__ qkv, float* __restrict__ o)
{
    __shared__ float Qs[QT][DHD+4];
    __shared__ float Ks[KT][DHD+4];
    __shared__ float Sc[QT][SS+16];
    const int tid = threadIdx.x;
    const int bh = blockIdx.y;
    const int b = bh >> 3, h = bh & 7;
    const int q0 = blockIdx.x * QT;
    const size_t rs = 3*D;
    const float* qb = qkv + (size_t)b*SS*rs;
    // load Q tile
    for (int i = tid; i < QT*(DHD/4); i += 256) {
        int q = i >> 5, dc = (i & 31) << 2;
        float4 v = *reinterpret_cast<const float4*>(qb + (size_t)(q0+q)*rs + h*DHD + dc);
        *reinterpret_cast<float4*>(&Qs[q][dc]) = v;
    }
    const float scale = 0.08838834764831845f;  // 1/sqrt(128)
    for (int kt = 0; kt < SS; kt += KT) {
        __syncthreads();
        for (int i = tid; i < KT*(DHD/4); i += 256) {
            int kk = i >> 5, dc = (i & 31) << 2;
            float4 v = *reinterpret_cast<const float4*>(qb + (size_t)(kt+kk)*rs + D + h*DHD + dc);
            *reinterpret_cast<float4*>(&Ks[kk][dc]) = v;
        }
        __syncthreads();
        for (int t = tid; t < QT*KT; t += 256) {
            int q = t >> 5, kk = t & 31;
            float s = 0.f;
            #pragma unroll
            for (int d = 0; d < DHD; d += 4) {
                float4 qv = *reinterpret_cast<const float4*>(&Qs[q][d]);
                float4 kv = *reinterpret_cast<const float4*>(&Ks[kk][d]);
                s += qv.x*kv.x + qv.y*kv.y + qv.z*kv.z + qv.w*kv.w;
            }
            Sc[q][kt+kk] = s*scale;
        }
    }
    __syncthreads();
    // softmax: 16 consecutive lanes per query
    {
        const int q = tid >> 4, lane = tid & 15;
        float mx = -1e30f;
        for (int j = lane; j < SS; j += 16) mx = fmaxf(mx, Sc[q][j]);
        #pragma unroll
        for (int off = 8; off; off >>= 1) mx = fmaxf(mx, __shfl_xor(mx, off, 16));
        float sum = 0.f;
        for (int j = lane; j < SS; j += 16) { float e = __expf(Sc[q][j]-mx); Sc[q][j]=e; sum += e; }
        #pragma unroll
        for (int off = 8; off; off >>= 1) sum += __shfl_xor(sum, off, 16);
        const float inv = 1.0f/sum;
        for (int j = lane; j < SS; j += 16) Sc[q][j] *= inv;
    }
    // P @ V
    const int q = tid >> 4;
    const int dbase = (tid & 15) << 3;
    float acc[8] = {};
    for (int kt = 0; kt < SS; kt += KT) {
        __syncthreads();
        for (int i = tid; i < KT*(DHD/4); i += 256) {
            int kk = i >> 5, dc = (i & 31) << 2;
            float4 v = *reinterpret_cast<const float4*>(qb + (size_t)(kt+kk)*rs + 2*D + h*DHD + dc);
            *reinterpret_cast<float4*>(&Ks[kk][dc]) = v;
        }
        __syncthreads();
        #pragma unroll 4
        for (int kk = 0; kk < KT; ++kk) {
            float p = Sc[q][kt+kk];
            float4 v0 = *reinterpret_cast<const float4*>(&Ks[kk][dbase]);
            float4 v1 = *reinterpret_cast<const float4*>(&Ks[kk][dbase+4]);
            acc[0] += p*v0.x; acc[1] += p*v0.y; acc[2] += p*v0.z; acc[3] += p*v0.w;
            acc[4] += p*v1.x; acc[5] += p*v1.y; acc[6] += p*v1.z; acc[7] += p*v1.w;
        }
    }
    float* orow = o + (size_t)(b*SS + q0 + q)*D + h*DHD + dbase;
    #pragma unroll
    for (int j = 0; j < 8; ++j) orow[j] = acc[j];
}

// =====================================================================
// fused residual + LayerNorm: xout = LN(xin + delta) * s + b  (row = block)
// =====================================================================
__global__ __launch_bounds__(256)
void add_ln(const float* __restrict__ xin, const float* __restrict__ delta,
            const float* __restrict__ gs, const float* __restrict__ gb,
            float* __restrict__ xout)
{
    const int row = blockIdx.x, tid = threadIdx.x;
    const size_t off = (size_t)row*D + tid*4;
    float4 a  = *reinterpret_cast<const float4*>(xin + off);
    float4 dd = *reinterpret_cast<const float4*>(delta + off);
    float v0=a.x+dd.x, v1=a.y+dd.y, v2=a.z+dd.z, v3=a.w+dd.w;
    __shared__ float red[2][4];
    float s = v0+v1+v2+v3;
    #pragma unroll
    for (int o = 32; o; o >>= 1) s += __shfl_xor(s, o, 64);
    if ((tid & 63) == 0) red[0][tid>>6] = s;
    __syncthreads();
    const float mean = (red[0][0]+red[0][1]+red[0][2]+red[0][3]) * (1.0f/D);
    v0-=mean; v1-=mean; v2-=mean; v3-=mean;
    float qv = v0*v0+v1*v1+v2*v2+v3*v3;
    #pragma unroll
    for (int o = 32; o; o >>= 1) qv += __shfl_xor(qv, o, 64);
    if ((tid & 63) == 0) red[1][tid>>6] = qv;
    __syncthreads();
    const float var = (red[1][0]+red[1][1]+red[1][2]+red[1][3]) * (1.0f/D);
    const float rstd = rsqrtf(var + EPSV);
    float4 sv = *reinterpret_cast<const float4*>(gs + tid*4);
    float4 bv = *reinterpret_cast<const float4*>(gb + tid*4);
    float4 ov;
    ov.x = v0*rstd*sv.x + bv.x;
    ov.y = v1*rstd*sv.y + bv.y;
    ov.z = v2*rstd*sv.z + bv.z;
    ov.w = v3*rstd*sv.w + bv.w;
    *reinterpret_cast<float4*>(xout + off) = ov;
}

// =====================================================================
// gate: logits = x@Wg^T + bg -> softmax -> top2 (first-occurrence ties)
// =====================================================================
__global__ __launch_bounds__(256)
void gate_kernel(const float* __restrict__ x, const float* __restrict__ Wg,
                 const float* __restrict__ bg, float* __restrict__ gv, int* __restrict__ gi)
{
    const int t = blockIdx.x, tid = threadIdx.x;
    const float* xr = x + (size_t)t*D;
    float p0=0,p1=0,p2=0,p3=0;
    for (int d = tid; d < D; d += 256) {
        const float xv = xr[d];
        p0 += xv*Wg[d]; p1 += xv*Wg[D+d]; p2 += xv*Wg[2*D+d]; p3 += xv*Wg[3*D+d];
    }
    #pragma unroll
    for (int o = 32; o; o >>= 1) {
        p0 += __shfl_xor(p0, o, 64); p1 += __shfl_xor(p1, o, 64);
        p2 += __shfl_xor(p2, o, 64); p3 += __shfl_xor(p3, o, 64);
    }
    __shared__ float red[4][4];
    if ((tid & 63) == 0) { const int w = tid>>6; red[w][0]=p0; red[w][1]=p1; red[w][2]=p2; red[w][3]=p3; }
    __syncthreads();
    if (tid == 0) {
        float g[4];
        #pragma unroll
        for (int e = 0; e < 4; ++e) g[e] = red[0][e]+red[1][e]+red[2][e]+red[3][e] + bg[e];
        const float mx = fmaxf(fmaxf(g[0],g[1]), fmaxf(g[2],g[3]));
        float ssum = 0.f;
        #pragma unroll
        for (int e = 0; e < 4; ++e) { g[e] = __expf(g[e]-mx); ssum += g[e]; }
        const float inv = 1.0f/ssum;
        #pragma unroll
        for (int e = 0; e < 4; ++e) g[e] *= inv;
        int i0 = 0;
        for (int e = 1; e < 4; ++e) if (g[e] > g[i0]) i0 = e;
        int i1 = (i0 == 0) ? 1 : 0;
        for (int e = 0; e < 4; ++e) if (e != i0 && g[e] > g[i1]) i1 = e;
        gv[t*2]   = g[i0]; gv[t*2+1] = g[i1];
        gi[t*2]   = i0;    gi[t*2+1] = i1;
    }
}

// =====================================================================
// MoE combine: x = x*(1-s) + s*(v0*E[i0] + v1*E[i1])   (eo includes be)
// =====================================================================
__global__ __launch_bounds__(256)
void moe_combine(float* __restrict__ x, const float* __restrict__ eo,
                 const float* __restrict__ gv, const int* __restrict__ gi)
{
    const size_t i = (size_t)blockIdx.x*256 + threadIdx.x;   // < TT*D
    const int t = (int)(i >> 10);                            // /D (D=1024)
    const float w0 = gv[t*2]*SPARS, w1 = gv[t*2+1]*SPARS;
    const size_t TD = (size_t)TT*D;
    const float e0 = eo[(size_t)gi[t*2]*TD + i];
    const float e1 = eo[(size_t)gi[t*2+1]*TD + i];
    x[i] = x[i]*(1.0f-SPARS) + w0*e0 + w1*e1;
}

__global__ __launch_bounds__(256)
void addpos(const float* __restrict__ xin, const float* __restrict__ pos, float* __restrict__ xo)
{
    const size_t i = (size_t)blockIdx.x*256 + threadIdx.x;   // < BB*SS*D
    xo[i] = xin[i] + pos[i & ((size_t)SS*D - 1)];            // SS*D = 2^19
}

__global__ __launch_bounds__(64)
void final_kernel(const float* __restrict__ x, const float* __restrict__ Wf,
                  const float* __restrict__ bf, float* __restrict__ out)
{
    const int b = blockIdx.x / NCLS, n = blockIdx.x % NCLS;
    const float* xr = x + ((size_t)b*SS + SS-1)*D;
    const int tid = threadIdx.x;
    float s = 0.f;
    for (int d = tid; d < D; d += 64) s += xr[d]*Wf[(size_t)n*D + d];
    #pragma unroll
    for (int o = 32; o; o >>= 1) s += __shfl_xor(s, o, 64);
    if (tid == 0) out[b*NCLS + n] = s + bf[n];
}

// =====================================================================
extern "C" void kernel_launch(void* const* d_in, const int* in_sizes, int n_in,
                              void* d_out, int out_size, void* d_ws, size_t ws_size,
                              hipStream_t stream)
{
    const float* x_in = (const float*)d_in[0];
    const float* pos  = (const float*)d_in[1];
    const float* Wqkv = (const float*)d_in[2];
    const float* bqkv = (const float*)d_in[3];
    const float* Wo   = (const float*)d_in[4];
    const float* bo   = (const float*)d_in[5];
    const float* ln1s = (const float*)d_in[6];
    const float* ln1b = (const float*)d_in[7];
    const float* W1   = (const float*)d_in[8];
    const float* b1   = (const float*)d_in[9];
    const float* W2   = (const float*)d_in[10];
    const float* b2   = (const float*)d_in[11];
    const float* ln2s = (const float*)d_in[12];
    const float* ln2b = (const float*)d_in[13];
    const float* Wg   = (const float*)d_in[14];
    const float* bg   = (const float*)d_in[15];
    const float* We   = (const float*)d_in[16];
    const float* be   = (const float*)d_in[17];
    const float* Wf   = (const float*)d_in[18];
    const float* bf   = (const float*)d_in[19];
    float* out = (float*)d_out;

    // workspace layout (floats): total ~14.7M floats ~= 59 MB
    float* ws     = (float*)d_ws;
    float* xbuf   = ws;                          // TT*D      (8 MB)
    float* qkvbuf = xbuf   + (size_t)TT*D;       // TT*3D     (24 MB)
    float* hbuf   = qkvbuf + (size_t)TT*3*D;     // TT*FF     (16 MB)
    float* obuf   = hbuf   + (size_t)TT*FF;      // TT*D      (8 MB)
    float* gv     = obuf   + (size_t)TT*D;       // TT*2
    int*   gi     = (int*)(gv + (size_t)TT*2);   // TT*2
    // expert outputs alias the (dead at that point) qkv+h region: NE*TT*D = 8.39M floats <= 10.5M
    float* ebuf   = qkvbuf;

    const dim3 blk(256);
    addpos<<<dim3(TT*D/256), blk, 0, stream>>>(x_in, pos, xbuf);

    for (int l = 0; l < NL; ++l) {
        // qkv = x @ Wqkv^T + b
        gemm_mfma<0><<<dim3(3*D/128, TT/128, 1), blk, 0, stream>>>(
            xbuf, Wqkv + (size_t)l*3*D*D, bqkv + (size_t)l*3*D, qkvbuf, TT, 3*D, D, 0, 0, 0);
        // attention -> obuf
        attn_kernel<<<dim3(SS/QT, BB*NH), blk, 0, stream>>>(qkvbuf, obuf);
        // o-proj -> hbuf (temp)
        gemm_mfma<0><<<dim3(D/128, TT/128, 1), blk, 0, stream>>>(
            obuf, Wo + (size_t)l*D*D, bo + (size_t)l*D, hbuf, TT, D, D, 0, 0, 0);
        // x = LN(x + oproj)
        add_ln<<<dim3(TT), blk, 0, stream>>>(xbuf, hbuf, ln1s + (size_t)l*D, ln1b + (size_t)l*D, xbuf);
        // h = gelu(x @ W1^T + b1)
        gemm_mfma<1><<<dim3(FF/128, TT/128, 1), blk, 0, stream>>>(
            xbuf, W1 + (size_t)l*FF*D, b1 + (size_t)l*FF, hbuf, TT, FF, D, 0, 0, 0);
        // f2 = h @ W2^T + b2 -> obuf
        gemm_mfma<0><<<dim3(D/128, TT/128, 1), blk, 0, stream>>>(
            hbuf, W2 + (size_t)l*D*FF, b2 + (size_t)l*D, obuf, TT, D, FF, 0, 0, 0);
        // x = LN(x + f2)
        add_ln<<<dim3(TT), blk, 0, stream>>>(xbuf, obuf, ln2s + (size_t)l*D, ln2b + (size_t)l*D, xbuf);
        // gate + top2
        gate_kernel<<<dim3(TT), blk, 0, stream>>>(xbuf, Wg, bg, gv, gi);
        // all 4 expert outputs in ONE launch (z = expert)
        gemm_mfma<0><<<dim3(D/128, TT/128, NE), blk, 0, stream>>>(
            xbuf, We, be, ebuf, TT, D, D, (long)D*D, (long)D, (long)TT*D);
        // x = x*0.5 + 0.5*(v0*E0 + v1*E1)
        moe_combine<<<dim3(TT*D/256), blk, 0, stream>>>(xbuf, ebuf, gv, gi);
    }
    final_kernel<<<dim3(BB*NCLS), dim3(64), 0, stream>>>(xbuf, Wf, bf, out);
}

// Round 3
// 4060.663 us; speedup vs baseline: 3.4982x; 1.5173x over previous
//
#include <hip/hip_runtime.h>
#include <math.h>

// ---- problem constants (match reference) ----
#define D     1024
#define NH    8
#define DHD   128
#define NL    12
#define NE    4
#define FF    2048
#define NCLS  10
#define BB    4
#define SS    512
#define TT    (BB*SS)          // 2048 tokens
#define EPSV  1e-5f
#define SPARS 0.5f

typedef __attribute__((ext_vector_type(8))) short bf16x8;
typedef __attribute__((ext_vector_type(4))) float f32x4;
typedef unsigned short ushortT;

__device__ __forceinline__ ushortT f2bf(float f) {
    unsigned u = __float_as_uint(f);
    u += 0x7FFF + ((u >> 16) & 1);      // RNE
    return (ushortT)(u >> 16);
}
__device__ __forceinline__ float bf2f(ushortT h) {
    return __uint_as_float(((unsigned)h) << 16);
}

// =====================================================================
// MFMA GEMM: C[M,N] = act(A[M,K] @ Bw[N,K]^T + bias[N])
// fp32 in global, bf16 conversion at LDS staging, fp32 accum/out.
// 128x128 tile, BK=32, 4 waves each owning a 64x64 quadrant (4x4 frags).
// =====================================================================
#define LDP 40   // LDS row pitch in bf16 elems (32 data + 8 pad)

template<int ACT>
__global__ __launch_bounds__(256)
void gemm_mfma(const float* __restrict__ A, const float* __restrict__ Bw,
               const float* __restrict__ bias, float* __restrict__ C,
               int M, int N, int K, long eBw, long eBias, long eC)
{
    const int z = blockIdx.z;
    Bw   += (size_t)z * eBw;
    bias += (size_t)z * eBias;
    C    += (size_t)z * eC;

    __shared__ ushortT Asl[128 * LDP];
    __shared__ ushortT Bsl[128 * LDP];

    const int tid  = threadIdx.x;
    const int wave = tid >> 6, lane = tid & 63;
    const int wm = (wave >> 1) * 64;
    const int wn = (wave & 1) * 64;
    const int fr = lane & 15;
    const int fq = lane >> 4;

    const int m0 = blockIdx.y * 128;
    const int n0 = blockIdx.x * 128;

    const int srow = tid >> 3;
    const int scb  = tid & 7;
    const float* Ag = A  + (size_t)(m0 + srow) * K + scb * 4;
    const float* Bg = Bw + (size_t)(n0 + srow) * K + scb * 4;

    f32x4 acc[4][4] = {};

    for (int k0 = 0; k0 < K; k0 += 32) {
        float4 av[4], bv[4];
        #pragma unroll
        for (int p = 0; p < 4; ++p) {
            av[p] = *reinterpret_cast<const float4*>(Ag + (size_t)(32*p) * K + k0);
            bv[p] = *reinterpret_cast<const float4*>(Bg + (size_t)(32*p) * K + k0);
        }
        __syncthreads();
        #pragma unroll
        for (int p = 0; p < 4; ++p) {
            const int r = srow + 32*p;
            ushort4 a4; a4.x=f2bf(av[p].x); a4.y=f2bf(av[p].y); a4.z=f2bf(av[p].z); a4.w=f2bf(av[p].w);
            ushort4 b4; b4.x=f2bf(bv[p].x); b4.y=f2bf(bv[p].y); b4.z=f2bf(bv[p].z); b4.w=f2bf(bv[p].w);
            *reinterpret_cast<ushort4*>(&Asl[r*LDP + scb*4]) = a4;
            *reinterpret_cast<ushort4*>(&Bsl[r*LDP + scb*4]) = b4;
        }
        __syncthreads();

        bf16x8 af[4], bf_[4];
        #pragma unroll
        for (int i = 0; i < 4; ++i) {
            af[i]  = *reinterpret_cast<const bf16x8*>(&Asl[(wm + i*16 + fr)*LDP + fq*8]);
            bf_[i] = *reinterpret_cast<const bf16x8*>(&Bsl[(wn + i*16 + fr)*LDP + fq*8]);
        }
        #pragma unroll
        for (int i = 0; i < 4; ++i)
            #pragma unroll
            for (int j = 0; j < 4; ++j)
                acc[i][j] = __builtin_amdgcn_mfma_f32_16x16x32_bf16(af[i], bf_[j], acc[i][j], 0, 0, 0);
    }

    #pragma unroll
    for (int j = 0; j < 4; ++j) {
        const int n = n0 + wn + j*16 + fr;
        const float bb = bias[n];
        #pragma unroll
        for (int i = 0; i < 4; ++i) {
            const int mbase = m0 + wm + i*16 + fq*4;
            #pragma unroll
            for (int r = 0; r < 4; ++r) {
                float u = acc[i][j][r] + bb;
                if (ACT == 1) u = 0.5f*u*(1.0f + erff(u*0.70710678118654752f));
                C[(size_t)(mbase + r) * N + n] = u;
            }
        }
    }
}

// =====================================================================
// kv_prep: per layer, from qkvbuf [token][3D] produce
//   Kb[bh][s][d]  bf16  (straight convert)
//   Vt[bh][d][s]  bf16  (transposed via LDS tile)
// grid (8 stiles, 32 bh), 256 threads; block handles 64 s x 128 d.
// =====================================================================
__global__ __launch_bounds__(256)
void kv_prep(const float* __restrict__ qkv, ushortT* __restrict__ Kb, ushortT* __restrict__ Vt)
{
    __shared__ ushortT T[64*136];   // V tile [s][d], pitch 136
    const int tid = threadIdx.x;
    const int st = blockIdx.x, bh = blockIdx.y;
    const int b = bh >> 3, h = bh & 7;
    const float* base = qkv + (size_t)(b*SS + st*64)*3*D + h*DHD;

    #pragma unroll
    for (int p = 0; p < 4; ++p) {
        const int row = (tid >> 4) + 16*p;        // 0..63 (s within tile)
        const int colb = (tid & 15) * 8;          // 0..120 (d)
        // K convert
        {
            const float* src = base + (size_t)row*3*D + D + colb;
            float f[8];
            *reinterpret_cast<float4*>(f)   = *reinterpret_cast<const float4*>(src);
            *reinterpret_cast<float4*>(f+4) = *reinterpret_cast<const float4*>(src+4);
            bf16x8 u;
            #pragma unroll
            for (int e = 0; e < 8; ++e) ((ushortT*)&u)[e] = f2bf(f[e]);
            *reinterpret_cast<bf16x8*>(&Kb[((size_t)bh*SS + st*64 + row)*DHD + colb]) = u;
        }
        // V convert -> LDS tile
        {
            const float* src = base + (size_t)row*3*D + 2*D + colb;
            float f[8];
            *reinterpret_cast<float4*>(f)   = *reinterpret_cast<const float4*>(src);
            *reinterpret_cast<float4*>(f+4) = *reinterpret_cast<const float4*>(src+4);
            #pragma unroll
            for (int e = 0; e < 8; ++e) T[row*136 + colb + e] = f2bf(f[e]);
        }
    }
    __syncthreads();
    // write V transposed: 128 d-rows x 64 s
    #pragma unroll
    for (int p = 0; p < 4; ++p) {
        const int d  = (tid >> 3) + 32*p;         // 0..127
        const int sb = (tid & 7) * 8;             // 0..56
        bf16x8 u;
        #pragma unroll
        for (int e = 0; e < 8; ++e) ((ushortT*)&u)[e] = T[(sb + e)*136 + d];
        *reinterpret_cast<bf16x8*>(&Vt[((size_t)bh*DHD + d)*SS + st*64 + sb]) = u;
    }
}

// =====================================================================
// attn_mfma: flash attention, bf16 MFMA, online softmax.
// grid (8 qtiles, 32 bh), 256 threads = 4 waves x 16 q-rows.
// Q read fp32 from qkv (pre-scaled, split hi/lo bf16); K from Kb; V from Vt.
// =====================================================================
#define KLP 136   // K lds pitch (bf16 elems), 128 + 8
#define VLP 72    // Vt lds pitch, 64 + 8
#define PLP 72    // P lds pitch, 64 + 8

__global__ __launch_bounds__(256)
void attn_mfma(const float* __restrict__ qkv, const ushortT* __restrict__ Kb,
               const ushortT* __restrict__ Vt, float* __restrict__ o)
{
    __shared__ ushortT Kl[64*KLP];     // [key][d]
    __shared__ ushortT Vl[128*VLP];    // [d][key]
    __shared__ ushortT Pl[4*16*PLP];   // per-wave [q][key]

    const int tid = threadIdx.x;
    const int w = tid >> 6, lane = tid & 63;
    const int g = lane >> 4, c = lane & 15;
    const int bh = blockIdx.y;
    const int b = bh >> 3, h = bh & 7;
    const int q0 = blockIdx.x*64 + w*16;
    ushortT* Pw = Pl + w*16*PLP;

    // ---- load Q fragments (scaled, hi/lo split) ----
    bf16x8 qhi[4], qlo[4];
    const float scale = 0.08838834764831845f;   // 1/sqrt(128)
    {
        const float* Qrow = qkv + (size_t)(b*SS + q0 + c)*3*D + h*DHD;
        #pragma unroll
        for (int db = 0; db < 4; ++db) {
            float f[8];
            *reinterpret_cast<float4*>(f)   = *reinterpret_cast<const float4*>(Qrow + db*32 + g*8);
            *reinterpret_cast<float4*>(f+4) = *reinterpret_cast<const float4*>(Qrow + db*32 + g*8 + 4);
            #pragma unroll
            for (int e = 0; e < 8; ++e) {
                const float fs = f[e]*scale;
                const ushortT hi = f2bf(fs);
                ((ushortT*)&qhi[db])[e] = hi;
                ((ushortT*)&qlo[db])[e] = f2bf(fs - bf2f(hi));
            }
        }
    }

    const ushortT* Kg = Kb + (size_t)bh*SS*DHD;
    const ushortT* Vg = Vt + (size_t)bh*DHD*SS;

    float m_r[4], l_r[4];
    #pragma unroll
    for (int r = 0; r < 4; ++r) { m_r[r] = -1e30f; l_r[r] = 0.f; }
    f32x4 oacc[8] = {};

    for (int kt = 0; kt < SS/64; ++kt) {
        __syncthreads();
        // stage K tile [64 keys][128 d]
        #pragma unroll
        for (int p = 0; p < 4; ++p) {
            const int row = (tid >> 4) + 16*p;
            const int colb = (tid & 15)*8;
            bf16x8 u = *reinterpret_cast<const bf16x8*>(&Kg[(size_t)(kt*64 + row)*DHD + colb]);
            *reinterpret_cast<bf16x8*>(&Kl[row*KLP + colb]) = u;
        }
        // stage Vt tile [128 d][64 keys]
        #pragma unroll
        for (int p = 0; p < 4; ++p) {
            const int dr = (tid >> 3) + 32*p;
            const int sb = (tid & 7)*8;
            bf16x8 u = *reinterpret_cast<const bf16x8*>(&Vg[(size_t)dr*SS + kt*64 + sb]);
            *reinterpret_cast<bf16x8*>(&Vl[dr*VLP + sb]) = u;
        }
        __syncthreads();

        // ---- QK^T: S[16q][64k], q = g*4+r (C rows), key = kb*16+c (C cols) ----
        f32x4 s[4] = {};
        #pragma unroll
        for (int db = 0; db < 4; ++db) {
            bf16x8 kf[4];
            #pragma unroll
            for (int kb = 0; kb < 4; ++kb)
                kf[kb] = *reinterpret_cast<const bf16x8*>(&Kl[(kb*16 + c)*KLP + db*32 + g*8]);
            #pragma unroll
            for (int kb = 0; kb < 4; ++kb) {
                s[kb] = __builtin_amdgcn_mfma_f32_16x16x32_bf16(qhi[db], kf[kb], s[kb], 0, 0, 0);
                s[kb] = __builtin_amdgcn_mfma_f32_16x16x32_bf16(qlo[db], kf[kb], s[kb], 0, 0, 0);
            }
        }

        // ---- online softmax ----
        float tmax[4];
        #pragma unroll
        for (int r = 0; r < 4; ++r) {
            tmax[r] = fmaxf(fmaxf(s[0][r], s[1][r]), fmaxf(s[2][r], s[3][r]));
        }
        #pragma unroll
        for (int off = 1; off < 16; off <<= 1)
            #pragma unroll
            for (int r = 0; r < 4; ++r)
                tmax[r] = fmaxf(tmax[r], __shfl_xor(tmax[r], off));
        float mn[4], corr[4];
        #pragma unroll
        for (int r = 0; r < 4; ++r) {
            mn[r] = fmaxf(m_r[r], tmax[r]);
            corr[r] = __expf(m_r[r] - mn[r]);
            m_r[r] = mn[r];
        }
        float tsum[4] = {0.f, 0.f, 0.f, 0.f};
        #pragma unroll
        for (int kb = 0; kb < 4; ++kb)
            #pragma unroll
            for (int r = 0; r < 4; ++r) {
                const float p = __expf(s[kb][r] - mn[r]);
                s[kb][r] = p;
                tsum[r] += p;
            }
        #pragma unroll
        for (int off = 1; off < 16; off <<= 1)
            #pragma unroll
            for (int r = 0; r < 4; ++r)
                tsum[r] += __shfl_xor(tsum[r], off);
        #pragma unroll
        for (int r = 0; r < 4; ++r) l_r[r] = l_r[r]*corr[r] + tsum[r];
        #pragma unroll
        for (int df = 0; df < 8; ++df)
            #pragma unroll
            for (int r = 0; r < 4; ++r)
                oacc[df][r] *= corr[r];

        // ---- P -> LDS (bf16), per-wave private ----
        #pragma unroll
        for (int kb = 0; kb < 4; ++kb)
            #pragma unroll
            for (int r = 0; r < 4; ++r)
                Pw[(g*4 + r)*PLP + kb*16 + c] = f2bf(s[kb][r]);

        // ---- PV: O[16q][128d] += P[16q][64k] @ V[64k][128d] ----
        #pragma unroll
        for (int kk = 0; kk < 2; ++kk) {
            bf16x8 pa = *reinterpret_cast<const bf16x8*>(&Pw[c*PLP + kk*32 + g*8]);
            #pragma unroll
            for (int df = 0; df < 8; ++df) {
                bf16x8 vb = *reinterpret_cast<const bf16x8*>(&Vl[(df*16 + c)*VLP + kk*32 + g*8]);
                oacc[df] = __builtin_amdgcn_mfma_f32_16x16x32_bf16(pa, vb, oacc[df], 0, 0, 0);
            }
        }
    }

    // ---- epilogue: o[q][d] = acc/l ----
    #pragma unroll
    for (int r = 0; r < 4; ++r) {
        const float inv = 1.0f / l_r[r];
        float* orow = o + (size_t)(b*SS + q0 + g*4 + r)*D + h*DHD + c;
        #pragma unroll
        for (int df = 0; df < 8; ++df)
            orow[df*16] = oacc[df][r] * inv;
    }
}

// =====================================================================
// fused residual + LayerNorm
// =====================================================================
__global__ __launch_bounds__(256)
void add_ln(const float* __restrict__ xin, const float* __restrict__ delta,
            const float* __restrict__ gs, const float* __restrict__ gb,
            float* __restrict__ xout)
{
    const int row = blockIdx.x, tid = threadIdx.x;
    const size_t off = (size_t)row*D + tid*4;
    float4 a  = *reinterpret_cast<const float4*>(xin + off);
    float4 dd = *reinterpret_cast<const float4*>(delta + off);
    float v0=a.x+dd.x, v1=a.y+dd.y, v2=a.z+dd.z, v3=a.w+dd.w;
    __shared__ float red[2][4];
    float s = v0+v1+v2+v3;
    #pragma unroll
    for (int o = 32; o; o >>= 1) s += __shfl_xor(s, o, 64);
    if ((tid & 63) == 0) red[0][tid>>6] = s;
    __syncthreads();
    const float mean = (red[0][0]+red[0][1]+red[0][2]+red[0][3]) * (1.0f/D);
    v0-=mean; v1-=mean; v2-=mean; v3-=mean;
    float qv = v0*v0+v1*v1+v2*v2+v3*v3;
    #pragma unroll
    for (int o = 32; o; o >>= 1) qv += __shfl_xor(qv, o, 64);
    if ((tid & 63) == 0) red[1][tid>>6] = qv;
    __syncthreads();
    const float var = (red[1][0]+red[1][1]+red[1][2]+red[1][3]) * (1.0f/D);
    const float rstd = rsqrtf(var + EPSV);
    float4 sv = *reinterpret_cast<const float4*>(gs + tid*4);
    float4 bv = *reinterpret_cast<const float4*>(gb + tid*4);
    float4 ov;
    ov.x = v0*rstd*sv.x + bv.x;
    ov.y = v1*rstd*sv.y + bv.y;
    ov.z = v2*rstd*sv.z + bv.z;
    ov.w = v3*rstd*sv.w + bv.w;
    *reinterpret_cast<float4*>(xout + off) = ov;
}

// =====================================================================
// gate: logits = x@Wg^T + bg -> softmax -> top2
// =====================================================================
__global__ __launch_bounds__(256)
void gate_kernel(const float* __restrict__ x, const float* __restrict__ Wg,
                 const float* __restrict__ bg, float* __restrict__ gv, int* __restrict__ gi)
{
    const int t = blockIdx.x, tid = threadIdx.x;
    const float* xr = x + (size_t)t*D;
    float p0=0,p1=0,p2=0,p3=0;
    for (int d = tid; d < D; d += 256) {
        const float xv = xr[d];
        p0 += xv*Wg[d]; p1 += xv*Wg[D+d]; p2 += xv*Wg[2*D+d]; p3 += xv*Wg[3*D+d];
    }
    #pragma unroll
    for (int o = 32; o; o >>= 1) {
        p0 += __shfl_xor(p0, o, 64); p1 += __shfl_xor(p1, o, 64);
        p2 += __shfl_xor(p2, o, 64); p3 += __shfl_xor(p3, o, 64);
    }
    __shared__ float red[4][4];
    if ((tid & 63) == 0) { const int w = tid>>6; red[w][0]=p0; red[w][1]=p1; red[w][2]=p2; red[w][3]=p3; }
    __syncthreads();
    if (tid == 0) {
        float g[4];
        #pragma unroll
        for (int e = 0; e < 4; ++e) g[e] = red[0][e]+red[1][e]+red[2][e]+red[3][e] + bg[e];
        const float mx = fmaxf(fmaxf(g[0],g[1]), fmaxf(g[2],g[3]));
        float ssum = 0.f;
        #pragma unroll
        for (int e = 0; e < 4; ++e) { g[e] = __expf(g[e]-mx); ssum += g[e]; }
        const float inv = 1.0f/ssum;
        #pragma unroll
        for (int e = 0; e < 4; ++e) g[e] *= inv;
        int i0 = 0;
        for (int e = 1; e < 4; ++e) if (g[e] > g[i0]) i0 = e;
        int i1 = (i0 == 0) ? 1 : 0;
        for (int e = 0; e < 4; ++e) if (e != i0 && g[e] > g[i1]) i1 = e;
        gv[t*2]   = g[i0]; gv[t*2+1] = g[i1];
        gi[t*2]   = i0;    gi[t*2+1] = i1;
    }
}

__global__ __launch_bounds__(256)
void moe_combine(float* __restrict__ x, const float* __restrict__ eo,
                 const float* __restrict__ gv, const int* __restrict__ gi)
{
    const size_t i = (size_t)blockIdx.x*256 + threadIdx.x;
    const int t = (int)(i >> 10);
    const float w0 = gv[t*2]*SPARS, w1 = gv[t*2+1]*SPARS;
    const size_t TD = (size_t)TT*D;
    const float e0 = eo[(size_t)gi[t*2]*TD + i];
    const float e1 = eo[(size_t)gi[t*2+1]*TD + i];
    x[i] = x[i]*(1.0f-SPARS) + w0*e0 + w1*e1;
}

__global__ __launch_bounds__(256)
void addpos(const float* __restrict__ xin, const float* __restrict__ pos, float* __restrict__ xo)
{
    const size_t i = (size_t)blockIdx.x*256 + threadIdx.x;
    xo[i] = xin[i] + pos[i & ((size_t)SS*D - 1)];
}

__global__ __launch_bounds__(64)
void final_kernel(const float* __restrict__ x, const float* __restrict__ Wf,
                  const float* __restrict__ bf, float* __restrict__ out)
{
    const int b = blockIdx.x / NCLS, n = blockIdx.x % NCLS;
    const float* xr = x + ((size_t)b*SS + SS-1)*D;
    const int tid = threadIdx.x;
    float s = 0.f;
    for (int d = tid; d < D; d += 64) s += xr[d]*Wf[(size_t)n*D + d];
    #pragma unroll
    for (int o = 32; o; o >>= 1) s += __shfl_xor(s, o, 64);
    if (tid == 0) out[b*NCLS + n] = s + bf[n];
}

// =====================================================================
extern "C" void kernel_launch(void* const* d_in, const int* in_sizes, int n_in,
                              void* d_out, int out_size, void* d_ws, size_t ws_size,
                              hipStream_t stream)
{
    const float* x_in = (const float*)d_in[0];
    const float* pos  = (const float*)d_in[1];
    const float* Wqkv = (const float*)d_in[2];
    const float* bqkv = (const float*)d_in[3];
    const float* Wo   = (const float*)d_in[4];
    const float* bo   = (const float*)d_in[5];
    const float* ln1s = (const float*)d_in[6];
    const float* ln1b = (const float*)d_in[7];
    const float* W1   = (const float*)d_in[8];
    const float* b1   = (const float*)d_in[9];
    const float* W2   = (const float*)d_in[10];
    const float* b2   = (const float*)d_in[11];
    const float* ln2s = (const float*)d_in[12];
    const float* ln2b = (const float*)d_in[13];
    const float* Wg   = (const float*)d_in[14];
    const float* bg   = (const float*)d_in[15];
    const float* We   = (const float*)d_in[16];
    const float* be   = (const float*)d_in[17];
    const float* Wf   = (const float*)d_in[18];
    const float* bf   = (const float*)d_in[19];
    float* out = (float*)d_out;

    // workspace layout (floats): total ~14.7M floats ~= 59 MB
    float* ws     = (float*)d_ws;
    float* xbuf   = ws;                          // TT*D      (8 MB)
    float* qkvbuf = xbuf   + (size_t)TT*D;       // TT*3D     (24 MB)
    float* hbuf   = qkvbuf + (size_t)TT*3*D;     // TT*FF     (16 MB)
    float* obuf   = hbuf   + (size_t)TT*FF;      // TT*D      (8 MB)
    float* gv     = obuf   + (size_t)TT*D;       // TT*2
    int*   gi     = (int*)(gv + (size_t)TT*2);   // TT*2
    // expert outputs alias qkv+h region: NE*TT*D floats = 32 MB <= 40 MB
    float* ebuf   = qkvbuf;
    // bf16 K / transposed V live in hbuf (dead during attention): 4 MB + 4 MB
    ushortT* Kb = (ushortT*)hbuf;
    ushortT* Vt = Kb + (size_t)BB*NH*SS*DHD;

    const dim3 blk(256);
    addpos<<<dim3(TT*D/256), blk, 0, stream>>>(x_in, pos, xbuf);

    for (int l = 0; l < NL; ++l) {
        // qkv = x @ Wqkv^T + b
        gemm_mfma<0><<<dim3(3*D/128, TT/128, 1), blk, 0, stream>>>(
            xbuf, Wqkv + (size_t)l*3*D*D, bqkv + (size_t)l*3*D, qkvbuf, TT, 3*D, D, 0, 0, 0);
        // K/V bf16 prep (V transposed)
        kv_prep<<<dim3(SS/64, BB*NH), blk, 0, stream>>>(qkvbuf, Kb, Vt);
        // flash attention -> obuf
        attn_mfma<<<dim3(SS/64, BB*NH), blk, 0, stream>>>(qkvbuf, Kb, Vt, obuf);
        // o-proj -> hbuf (Kb/Vt dead from here)
        gemm_mfma<0><<<dim3(D/128, TT/128, 1), blk, 0, stream>>>(
            obuf, Wo + (size_t)l*D*D, bo + (size_t)l*D, hbuf, TT, D, D, 0, 0, 0);
        // x = LN(x + oproj)
        add_ln<<<dim3(TT), blk, 0, stream>>>(xbuf, hbuf, ln1s + (size_t)l*D, ln1b + (size_t)l*D, xbuf);
        // h = gelu(x @ W1^T + b1)
        gemm_mfma<1><<<dim3(FF/128, TT/128, 1), blk, 0, stream>>>(
            xbuf, W1 + (size_t)l*FF*D, b1 + (size_t)l*FF, hbuf, TT, FF, D, 0, 0, 0);
        // f2 = h @ W2^T + b2 -> obuf
        gemm_mfma<0><<<dim3(D/128, TT/128, 1), blk, 0, stream>>>(
            hbuf, W2 + (size_t)l*D*FF, b2 + (size_t)l*D, obuf, TT, D, FF, 0, 0, 0);
        // x = LN(x + f2)
        add_ln<<<dim3(TT), blk, 0, stream>>>(xbuf, obuf, ln2s + (size_t)l*D, ln2b + (size_t)l*D, xbuf);
        // gate + top2
        gate_kernel<<<dim3(TT), blk, 0, stream>>>(xbuf, Wg, bg, gv, gi);
        // all 4 expert outputs in ONE launch (z = expert)
        gemm_mfma<0><<<dim3(D/128, TT/128, NE), blk, 0, stream>>>(
            xbuf, We, be, ebuf, TT, D, D, (long)D*D, (long)D, (long)TT*D);
        // x = x*0.5 + 0.5*(v0*E0 + v1*E1)
        moe_combine<<<dim3(TT*D/256), blk, 0, stream>>>(xbuf, ebuf, gv, gi);
    }
    final_kernel<<<dim3(BB*NCLS), dim3(64), 0, stream>>>(xbuf, Wf, bf, out);
}

// Round 4
// 2870.966 us; speedup vs baseline: 4.9477x; 1.4144x over previous
//
#include <hip/hip_runtime.h>
#include <math.h>

// ---- problem constants (match reference) ----
#define D     1024
#define NH    8
#define DHD   128
#define NL    12
#define NE    4
#define FF    2048
#define NCLS  10
#define BB    4
#define SS    512
#define TT    (BB*SS)          // 2048 tokens
#define EPSV  1e-5f
#define SPARS 0.5f

typedef __attribute__((ext_vector_type(8))) short bf16x8;
typedef __attribute__((ext_vector_type(4))) float f32x4;
typedef unsigned short ushortT;

__device__ __forceinline__ ushortT f2bf(float f) {
    unsigned u = __float_as_uint(f);
    u += 0x7FFF + ((u >> 16) & 1);      // RNE
    return (ushortT)(u >> 16);
}
__device__ __forceinline__ float bf2f(ushortT h) {
    return __uint_as_float(((unsigned)h) << 16);
}

// =====================================================================
// MFMA GEMM: C[M,N] = act(A[M,K] @ Bw[N,K]^T + bias[N])
// A bf16 [M][Ktot]; Bw fp32 [N][Ktot] (bf16 convert at staging).
// 128x128 tile, BK=32, 4 waves each owning a 64x64 quadrant (4x4 frags).
// MODE: 0 = bf16 out, 1 = f32 out.  ACT: 1 = exact GELU.
// SK==1: blockIdx.z = batch (strides eBw/eBias/eC).
// SK>1 : blockIdx.z = K-chunk; out = f32 partial at C + z*M*N, no bias/act.
// =====================================================================
#define LDP 40   // LDS row pitch in bf16 elems (32 data + 8 pad)

template<int MODE, int SK, int ACT>
__global__ __launch_bounds__(256)
void gemm_mfma(const ushortT* __restrict__ A, const float* __restrict__ Bw,
               const float* __restrict__ bias, void* __restrict__ Cv,
               int M, int N, int Ktot, int Klen, long eBw, long eBias, long eC)
{
    const int z = blockIdx.z;
    int koff = 0;
    float* Cf = nullptr; ushortT* Ch = nullptr;
    if constexpr (SK > 1) {
        koff = z * Klen;
        Cf = (float*)Cv + (size_t)z * M * N;
    } else {
        Bw   += (size_t)z * eBw;
        bias += (size_t)z * eBias;
        if constexpr (MODE == 0) Ch = (ushortT*)Cv + (size_t)z * eC;
        else                     Cf = (float*)Cv   + (size_t)z * eC;
    }

    __shared__ ushortT Asl[128 * LDP];
    __shared__ ushortT Bsl[128 * LDP];

    const int tid  = threadIdx.x;
    const int wave = tid >> 6, lane = tid & 63;
    const int wm = (wave >> 1) * 64;
    const int wn = (wave & 1) * 64;
    const int fr = lane & 15;
    const int fq = lane >> 4;

    const int m0 = blockIdx.y * 128;
    const int n0 = blockIdx.x * 128;

    // A staging: 128 rows x 32 k bf16 = 512 x (8 bf16); 2 chunks/thread
    const int arow = tid >> 1;
    const int akc  = (tid & 1) * 2;
    const ushortT* Ag = A + (size_t)(m0 + arow) * Ktot + koff;
    // B staging: fp32, 128 rows x 32 k; 4 chunks/thread
    const int srow = tid >> 3;
    const int scb  = tid & 7;
    const float* Bg = Bw + (size_t)(n0 + srow) * Ktot + koff + scb * 4;

    f32x4 acc[4][4] = {};

    for (int k0 = 0; k0 < Klen; k0 += 32) {
        bf16x8 av8[2];
        float4 bv[4];
        #pragma unroll
        for (int u = 0; u < 2; ++u)
            av8[u] = *reinterpret_cast<const bf16x8*>(Ag + k0 + (akc + u) * 8);
        #pragma unroll
        for (int p = 0; p < 4; ++p)
            bv[p] = *reinterpret_cast<const float4*>(Bg + (size_t)(32*p) * Ktot + k0);
        __syncthreads();
        #pragma unroll
        for (int u = 0; u < 2; ++u)
            *reinterpret_cast<bf16x8*>(&Asl[arow*LDP + (akc + u)*8]) = av8[u];
        #pragma unroll
        for (int p = 0; p < 4; ++p) {
            const int r = srow + 32*p;
            ushort4 b4; b4.x=f2bf(bv[p].x); b4.y=f2bf(bv[p].y); b4.z=f2bf(bv[p].z); b4.w=f2bf(bv[p].w);
            *reinterpret_cast<ushort4*>(&Bsl[r*LDP + scb*4]) = b4;
        }
        __syncthreads();

        bf16x8 af[4], bf_[4];
        #pragma unroll
        for (int i = 0; i < 4; ++i) {
            af[i]  = *reinterpret_cast<const bf16x8*>(&Asl[(wm + i*16 + fr)*LDP + fq*8]);
            bf_[i] = *reinterpret_cast<const bf16x8*>(&Bsl[(wn + i*16 + fr)*LDP + fq*8]);
        }
        #pragma unroll
        for (int i = 0; i < 4; ++i)
            #pragma unroll
            for (int j = 0; j < 4; ++j)
                acc[i][j] = __builtin_amdgcn_mfma_f32_16x16x32_bf16(af[i], bf_[j], acc[i][j], 0, 0, 0);
    }

    #pragma unroll
    for (int j = 0; j < 4; ++j) {
        const int n = n0 + wn + j*16 + fr;
        float bb = 0.f;
        if constexpr (SK == 1) bb = bias[n];
        #pragma unroll
        for (int i = 0; i < 4; ++i) {
            const int mbase = m0 + wm + i*16 + fq*4;
            #pragma unroll
            for (int r = 0; r < 4; ++r) {
                float u = acc[i][j][r] + bb;
                if constexpr (SK == 1 && ACT == 1)
                    u = 0.5f*u*(1.0f + erff(u*0.70710678118654752f));
                if constexpr (SK > 1)       Cf[(size_t)(mbase + r) * N + n] = u;
                else if constexpr (MODE==0) Ch[(size_t)(mbase + r) * N + n] = f2bf(u);
                else                        Cf[(size_t)(mbase + r) * N + n] = u;
            }
        }
    }
}

// =====================================================================
// kv_prep: from qkvbuf fp32 [token][3D] produce
//   Kb[bh][s][d] bf16,  Vt[bh][d][s] bf16 (transposed via LDS tile)
// =====================================================================
__global__ __launch_bounds__(256)
void kv_prep(const float* __restrict__ qkv, ushortT* __restrict__ Kb, ushortT* __restrict__ Vt)
{
    __shared__ ushortT T[64*136];
    const int tid = threadIdx.x;
    const int st = blockIdx.x, bh = blockIdx.y;
    const int b = bh >> 3, h = bh & 7;
    const float* base = qkv + (size_t)(b*SS + st*64)*3*D + h*DHD;

    #pragma unroll
    for (int p = 0; p < 4; ++p) {
        const int row = (tid >> 4) + 16*p;
        const int colb = (tid & 15) * 8;
        {
            const float* src = base + (size_t)row*3*D + D + colb;
            float f[8];
            *reinterpret_cast<float4*>(f)   = *reinterpret_cast<const float4*>(src);
            *reinterpret_cast<float4*>(f+4) = *reinterpret_cast<const float4*>(src+4);
            bf16x8 u;
            #pragma unroll
            for (int e = 0; e < 8; ++e) ((ushortT*)&u)[e] = f2bf(f[e]);
            *reinterpret_cast<bf16x8*>(&Kb[((size_t)bh*SS + st*64 + row)*DHD + colb]) = u;
        }
        {
            const float* src = base + (size_t)row*3*D + 2*D + colb;
            float f[8];
            *reinterpret_cast<float4*>(f)   = *reinterpret_cast<const float4*>(src);
            *reinterpret_cast<float4*>(f+4) = *reinterpret_cast<const float4*>(src+4);
            #pragma unroll
            for (int e = 0; e < 8; ++e) T[row*136 + colb + e] = f2bf(f[e]);
        }
    }
    __syncthreads();
    #pragma unroll
    for (int p = 0; p < 4; ++p) {
        const int d  = (tid >> 3) + 32*p;
        const int sb = (tid & 7) * 8;
        bf16x8 u;
        #pragma unroll
        for (int e = 0; e < 8; ++e) ((ushortT*)&u)[e] = T[(sb + e)*136 + d];
        *reinterpret_cast<bf16x8*>(&Vt[((size_t)bh*DHD + d)*SS + st*64 + sb]) = u;
    }
}

// =====================================================================
// attn_mfma: flash attention, bf16 MFMA, online softmax. bf16 output.
// =====================================================================
#define KLP 136
#define VLP 72
#define PLP 72

__global__ __launch_bounds__(256)
void attn_mfma(const float* __restrict__ qkv, const ushortT* __restrict__ Kb,
               const ushortT* __restrict__ Vt, ushortT* __restrict__ o16)
{
    __shared__ ushortT Kl[64*KLP];
    __shared__ ushortT Vl[128*VLP];
    __shared__ ushortT Pl[4*16*PLP];

    const int tid = threadIdx.x;
    const int w = tid >> 6, lane = tid & 63;
    const int g = lane >> 4, c = lane & 15;
    const int bh = blockIdx.y;
    const int b = bh >> 3, h = bh & 7;
    const int q0 = blockIdx.x*64 + w*16;
    ushortT* Pw = Pl + w*16*PLP;

    bf16x8 qhi[4], qlo[4];
    const float scale = 0.08838834764831845f;
    {
        const float* Qrow = qkv + (size_t)(b*SS + q0 + c)*3*D + h*DHD;
        #pragma unroll
        for (int db = 0; db < 4; ++db) {
            float f[8];
            *reinterpret_cast<float4*>(f)   = *reinterpret_cast<const float4*>(Qrow + db*32 + g*8);
            *reinterpret_cast<float4*>(f+4) = *reinterpret_cast<const float4*>(Qrow + db*32 + g*8 + 4);
            #pragma unroll
            for (int e = 0; e < 8; ++e) {
                const float fs = f[e]*scale;
                const ushortT hi = f2bf(fs);
                ((ushortT*)&qhi[db])[e] = hi;
                ((ushortT*)&qlo[db])[e] = f2bf(fs - bf2f(hi));
            }
        }
    }

    const ushortT* Kg = Kb + (size_t)bh*SS*DHD;
    const ushortT* Vg = Vt + (size_t)bh*DHD*SS;

    float m_r[4], l_r[4];
    #pragma unroll
    for (int r = 0; r < 4; ++r) { m_r[r] = -1e30f; l_r[r] = 0.f; }
    f32x4 oacc[8] = {};

    for (int kt = 0; kt < SS/64; ++kt) {
        __syncthreads();
        #pragma unroll
        for (int p = 0; p < 4; ++p) {
            const int row = (tid >> 4) + 16*p;
            const int colb = (tid & 15)*8;
            bf16x8 u = *reinterpret_cast<const bf16x8*>(&Kg[(size_t)(kt*64 + row)*DHD + colb]);
            *reinterpret_cast<bf16x8*>(&Kl[row*KLP + colb]) = u;
        }
        #pragma unroll
        for (int p = 0; p < 4; ++p) {
            const int dr = (tid >> 3) + 32*p;
            const int sb = (tid & 7)*8;
            bf16x8 u = *reinterpret_cast<const bf16x8*>(&Vg[(size_t)dr*SS + kt*64 + sb]);
            *reinterpret_cast<bf16x8*>(&Vl[dr*VLP + sb]) = u;
        }
        __syncthreads();

        f32x4 s[4] = {};
        #pragma unroll
        for (int db = 0; db < 4; ++db) {
            bf16x8 kf[4];
            #pragma unroll
            for (int kb = 0; kb < 4; ++kb)
                kf[kb] = *reinterpret_cast<const bf16x8*>(&Kl[(kb*16 + c)*KLP + db*32 + g*8]);
            #pragma unroll
            for (int kb = 0; kb < 4; ++kb) {
                s[kb] = __builtin_amdgcn_mfma_f32_16x16x32_bf16(qhi[db], kf[kb], s[kb], 0, 0, 0);
                s[kb] = __builtin_amdgcn_mfma_f32_16x16x32_bf16(qlo[db], kf[kb], s[kb], 0, 0, 0);
            }
        }

        float tmax[4];
        #pragma unroll
        for (int r = 0; r < 4; ++r)
            tmax[r] = fmaxf(fmaxf(s[0][r], s[1][r]), fmaxf(s[2][r], s[3][r]));
        #pragma unroll
        for (int off = 1; off < 16; off <<= 1)
            #pragma unroll
            for (int r = 0; r < 4; ++r)
                tmax[r] = fmaxf(tmax[r], __shfl_xor(tmax[r], off));
        float mn[4], corr[4];
        #pragma unroll
        for (int r = 0; r < 4; ++r) {
            mn[r] = fmaxf(m_r[r], tmax[r]);
            corr[r] = __expf(m_r[r] - mn[r]);
            m_r[r] = mn[r];
        }
        float tsum[4] = {0.f, 0.f, 0.f, 0.f};
        #pragma unroll
        for (int kb = 0; kb < 4; ++kb)
            #pragma unroll
            for (int r = 0; r < 4; ++r) {
                const float p = __expf(s[kb][r] - mn[r]);
                s[kb][r] = p;
                tsum[r] += p;
            }
        #pragma unroll
        for (int off = 1; off < 16; off <<= 1)
            #pragma unroll
            for (int r = 0; r < 4; ++r)
                tsum[r] += __shfl_xor(tsum[r], off);
        #pragma unroll
        for (int r = 0; r < 4; ++r) l_r[r] = l_r[r]*corr[r] + tsum[r];
        #pragma unroll
        for (int df = 0; df < 8; ++df)
            #pragma unroll
            for (int r = 0; r < 4; ++r)
                oacc[df][r] *= corr[r];

        #pragma unroll
        for (int kb = 0; kb < 4; ++kb)
            #pragma unroll
            for (int r = 0; r < 4; ++r)
                Pw[(g*4 + r)*PLP + kb*16 + c] = f2bf(s[kb][r]);

        #pragma unroll
        for (int kk = 0; kk < 2; ++kk) {
            bf16x8 pa = *reinterpret_cast<const bf16x8*>(&Pw[c*PLP + kk*32 + g*8]);
            #pragma unroll
            for (int df = 0; df < 8; ++df) {
                bf16x8 vb = *reinterpret_cast<const bf16x8*>(&Vl[(df*16 + c)*VLP + kk*32 + g*8]);
                oacc[df] = __builtin_amdgcn_mfma_f32_16x16x32_bf16(pa, vb, oacc[df], 0, 0, 0);
            }
        }
    }

    #pragma unroll
    for (int r = 0; r < 4; ++r) {
        const float inv = 1.0f / l_r[r];
        ushortT* orow = o16 + (size_t)(b*SS + q0 + g*4 + r)*D + h*DHD + c;
        #pragma unroll
        for (int df = 0; df < 8; ++df)
            orow[df*16] = f2bf(oacc[df][r] * inv);
    }
}

// =====================================================================
// add_ln_r: xout = LN(xin + sum_s P[s] + dbias) * s + b
// writes fp32 + bf16; GATE: also computes gate softmax top-2.
// =====================================================================
template<int SK, int GATE>
__global__ __launch_bounds__(256)
void add_ln_r(const float* __restrict__ xin, const float* __restrict__ P,
              const float* __restrict__ dbias,
              const float* __restrict__ gs, const float* __restrict__ gb,
              float* __restrict__ x32, ushortT* __restrict__ x16,
              const float* __restrict__ Wg, const float* __restrict__ bg,
              float* __restrict__ gv, int* __restrict__ gi)
{
    const int row = blockIdx.x, tid = threadIdx.x;
    const size_t off = (size_t)row*D + tid*4;
    float4 a = *reinterpret_cast<const float4*>(xin + off);
    float d0, d1, d2, d3;
    {
        float4 bvd = *reinterpret_cast<const float4*>(dbias + tid*4);
        d0 = bvd.x; d1 = bvd.y; d2 = bvd.z; d3 = bvd.w;
    }
    #pragma unroll
    for (int s = 0; s < SK; ++s) {
        float4 pv = *reinterpret_cast<const float4*>(P + (size_t)s*TT*D + off);
        d0 += pv.x; d1 += pv.y; d2 += pv.z; d3 += pv.w;
    }
    float v0=a.x+d0, v1=a.y+d1, v2=a.z+d2, v3=a.w+d3;
    __shared__ float red[2][4];
    float s = v0+v1+v2+v3;
    #pragma unroll
    for (int o = 32; o; o >>= 1) s += __shfl_xor(s, o, 64);
    if ((tid & 63) == 0) red[0][tid>>6] = s;
    __syncthreads();
    const float mean = (red[0][0]+red[0][1]+red[0][2]+red[0][3]) * (1.0f/D);
    v0-=mean; v1-=mean; v2-=mean; v3-=mean;
    float qv = v0*v0+v1*v1+v2*v2+v3*v3;
    #pragma unroll
    for (int o = 32; o; o >>= 1) qv += __shfl_xor(qv, o, 64);
    if ((tid & 63) == 0) red[1][tid>>6] = qv;
    __syncthreads();
    const float var = (red[1][0]+red[1][1]+red[1][2]+red[1][3]) * (1.0f/D);
    const float rstd = rsqrtf(var + EPSV);
    float4 sv = *reinterpret_cast<const float4*>(gs + tid*4);
    float4 bv = *reinterpret_cast<const float4*>(gb + tid*4);
    float ov[4];
    ov[0] = v0*rstd*sv.x + bv.x;
    ov[1] = v1*rstd*sv.y + bv.y;
    ov[2] = v2*rstd*sv.z + bv.z;
    ov[3] = v3*rstd*sv.w + bv.w;
    float4 o4; o4.x=ov[0]; o4.y=ov[1]; o4.z=ov[2]; o4.w=ov[3];
    *reinterpret_cast<float4*>(x32 + off) = o4;
    ushort4 h4; h4.x=f2bf(ov[0]); h4.y=f2bf(ov[1]); h4.z=f2bf(ov[2]); h4.w=f2bf(ov[3]);
    *reinterpret_cast<ushort4*>(x16 + off) = h4;

    if constexpr (GATE) {
        float p[4] = {0.f, 0.f, 0.f, 0.f};
        #pragma unroll
        for (int e = 0; e < 4; ++e) {
            const float* wr = Wg + (size_t)e*D + tid*4;
            p[e] = ov[0]*wr[0] + ov[1]*wr[1] + ov[2]*wr[2] + ov[3]*wr[3];
        }
        #pragma unroll
        for (int o = 32; o; o >>= 1) {
            p[0] += __shfl_xor(p[0], o, 64); p[1] += __shfl_xor(p[1], o, 64);
            p[2] += __shfl_xor(p[2], o, 64); p[3] += __shfl_xor(p[3], o, 64);
        }
        __shared__ float gred[4][4];
        if ((tid & 63) == 0) {
            const int w = tid>>6;
            gred[w][0]=p[0]; gred[w][1]=p[1]; gred[w][2]=p[2]; gred[w][3]=p[3];
        }
        __syncthreads();
        if (tid == 0) {
            float g[4];
            #pragma unroll
            for (int e = 0; e < 4; ++e) g[e] = gred[0][e]+gred[1][e]+gred[2][e]+gred[3][e] + bg[e];
            const float mx = fmaxf(fmaxf(g[0],g[1]), fmaxf(g[2],g[3]));
            float ssum = 0.f;
            #pragma unroll
            for (int e = 0; e < 4; ++e) { g[e] = __expf(g[e]-mx); ssum += g[e]; }
            const float inv = 1.0f/ssum;
            #pragma unroll
            for (int e = 0; e < 4; ++e) g[e] *= inv;
            int i0 = 0;
            for (int e = 1; e < 4; ++e) if (g[e] > g[i0]) i0 = e;
            int i1 = (i0 == 0) ? 1 : 0;
            for (int e = 0; e < 4; ++e) if (e != i0 && g[e] > g[i1]) i1 = e;
            gv[row*2]   = g[i0]; gv[row*2+1] = g[i1];
            gi[row*2]   = i0;    gi[row*2+1] = i1;
        }
    }
}

// =====================================================================
__global__ __launch_bounds__(256)
void moe_combine(float* __restrict__ x, ushortT* __restrict__ x16,
                 const float* __restrict__ eo,
                 const float* __restrict__ gv, const int* __restrict__ gi)
{
    const size_t i = (size_t)blockIdx.x*256 + threadIdx.x;
    const int t = (int)(i >> 10);
    const float w0 = gv[t*2]*SPARS, w1 = gv[t*2+1]*SPARS;
    const size_t TD = (size_t)TT*D;
    const float e0 = eo[(size_t)gi[t*2]*TD + i];
    const float e1 = eo[(size_t)gi[t*2+1]*TD + i];
    const float r = x[i]*(1.0f-SPARS) + w0*e0 + w1*e1;
    x[i] = r;
    x16[i] = f2bf(r);
}

__global__ __launch_bounds__(256)
void addpos(const float* __restrict__ xin, const float* __restrict__ pos,
            float* __restrict__ xo, ushortT* __restrict__ x16)
{
    const size_t i = (size_t)blockIdx.x*256 + threadIdx.x;
    const float r = xin[i] + pos[i & ((size_t)SS*D - 1)];
    xo[i] = r;
    x16[i] = f2bf(r);
}

__global__ __launch_bounds__(64)
void final_kernel(const float* __restrict__ x, const float* __restrict__ Wf,
                  const float* __restrict__ bf, float* __restrict__ out)
{
    const int b = blockIdx.x / NCLS, n = blockIdx.x % NCLS;
    const float* xr = x + ((size_t)b*SS + SS-1)*D;
    const int tid = threadIdx.x;
    float s = 0.f;
    for (int d = tid; d < D; d += 64) s += xr[d]*Wf[(size_t)n*D + d];
    #pragma unroll
    for (int o = 32; o; o >>= 1) s += __shfl_xor(s, o, 64);
    if (tid == 0) out[b*NCLS + n] = s + bf[n];
}

// =====================================================================
extern "C" void kernel_launch(void* const* d_in, const int* in_sizes, int n_in,
                              void* d_out, int out_size, void* d_ws, size_t ws_size,
                              hipStream_t stream)
{
    const float* x_in = (const float*)d_in[0];
    const float* pos  = (const float*)d_in[1];
    const float* Wqkv = (const float*)d_in[2];
    const float* bqkv = (const float*)d_in[3];
    const float* Wo   = (const float*)d_in[4];
    const float* bo   = (const float*)d_in[5];
    const float* ln1s = (const float*)d_in[6];
    const float* ln1b = (const float*)d_in[7];
    const float* W1   = (const float*)d_in[8];
    const float* b1   = (const float*)d_in[9];
    const float* W2   = (const float*)d_in[10];
    const float* b2   = (const float*)d_in[11];
    const float* ln2s = (const float*)d_in[12];
    const float* ln2b = (const float*)d_in[13];
    const float* Wg   = (const float*)d_in[14];
    const float* bg   = (const float*)d_in[15];
    const float* We   = (const float*)d_in[16];
    const float* be   = (const float*)d_in[17];
    const float* Wf   = (const float*)d_in[18];
    const float* bf   = (const float*)d_in[19];
    float* out = (float*)d_out;

    // ---- workspace layout (floats), ~56 MB total ----
    float* ws     = (float*)d_ws;
    float*   xbuf  = ws;                                   // TT*D fp32      (8 MB)
    ushortT* xb16  = (ushortT*)(xbuf + (size_t)TT*D);      // TT*D bf16      (4 MB)
    ushortT* ob16  = xb16 + (size_t)TT*D;                  // TT*D bf16      (4 MB) attn out
    float*   scratch = (float*)(ob16 + (size_t)TT*D);      // 8M floats      (32 MB)
    ushortT* hb16  = (ushortT*)(scratch + (size_t)8*1024*1024/4*4);  // after 8M floats
    // (compute hb16 properly below)
    hb16 = (ushortT*)(scratch + (size_t)TT*D*4);           // scratch is 4*TT*D floats = 32 MB
    float*   gv    = (float*)(hb16 + (size_t)TT*FF);       // TT*2
    int*     gi    = (int*)(gv + (size_t)TT*2);            // TT*2
    // aliases inside scratch (time-disjoint):
    float*   qkvbuf = scratch;                             // TT*3D fp32 (24 MB)
    ushortT* Kb     = (ushortT*)(qkvbuf + (size_t)TT*3*D); // 4 MB
    ushortT* Vt     = Kb + (size_t)BB*NH*SS*DHD;           // 4 MB
    float*   parts  = scratch;                             // up to 4 x TT*D fp32 (32 MB)
    float*   ebuf   = scratch;                             // 4 x TT*D fp32 (32 MB)

    const dim3 blk(256);
    addpos<<<dim3(TT*D/256), blk, 0, stream>>>(x_in, pos, xbuf, xb16);

    for (int l = 0; l < NL; ++l) {
        // qkv = x @ Wqkv^T + b   (fp32 out for attention Q precision)
        gemm_mfma<1,1,0><<<dim3(3*D/128, TT/128, 1), blk, 0, stream>>>(
            xb16, Wqkv + (size_t)l*3*D*D, bqkv + (size_t)l*3*D, qkvbuf,
            TT, 3*D, D, D, 0, 0, 0);
        // K/V bf16 prep (V transposed)
        kv_prep<<<dim3(SS/64, BB*NH), blk, 0, stream>>>(qkvbuf, Kb, Vt);
        // flash attention -> ob16 (bf16)
        attn_mfma<<<dim3(SS/64, BB*NH), blk, 0, stream>>>(qkvbuf, Kb, Vt, ob16);
        // o-proj: splitK=4 partials (qkv/Kb/Vt dead from here)
        gemm_mfma<1,4,0><<<dim3(D/128, TT/128, 4), blk, 0, stream>>>(
            ob16, Wo + (size_t)l*D*D, bo, parts, TT, D, D, D/4, 0, 0, 0);
        // x = LN(x + sum(parts) + bo)
        add_ln_r<4,0><<<dim3(TT), blk, 0, stream>>>(
            xbuf, parts, bo + (size_t)l*D, ln1s + (size_t)l*D, ln1b + (size_t)l*D,
            xbuf, xb16, nullptr, nullptr, nullptr, nullptr);
        // h = gelu(x @ W1^T + b1) -> bf16
        gemm_mfma<0,1,1><<<dim3(FF/128, TT/128, 1), blk, 0, stream>>>(
            xb16, W1 + (size_t)l*FF*D, b1 + (size_t)l*FF, hb16, TT, FF, D, D, 0, 0, 0);
        // f2 = h @ W2^T: splitK=4 partials
        gemm_mfma<1,4,0><<<dim3(D/128, TT/128, 4), blk, 0, stream>>>(
            hb16, W2 + (size_t)l*D*FF, b2, parts, TT, D, FF, FF/4, 0, 0, 0);
        // x = LN(x + sum(parts) + b2)  + fused gate top-2
        add_ln_r<4,1><<<dim3(TT), blk, 0, stream>>>(
            xbuf, parts, b2 + (size_t)l*D, ln2s + (size_t)l*D, ln2b + (size_t)l*D,
            xbuf, xb16, Wg, bg, gv, gi);
        // all 4 expert outputs (z = expert), fp32 + bias
        gemm_mfma<1,1,0><<<dim3(D/128, TT/128, NE), blk, 0, stream>>>(
            xb16, We, be, ebuf, TT, D, D, D, (long)D*D, (long)D, (long)TT*D);
        // x = x*0.5 + 0.5*(v0*E0 + v1*E1)
        moe_combine<<<dim3(TT*D/256), blk, 0, stream>>>(xbuf, xb16, ebuf, gv, gi);
    }
    final_kernel<<<dim3(BB*NCLS), dim3(64), 0, stream>>>(xbuf, Wf, bf, out);
}